// Round 4
// baseline (172.559 us; speedup 1.0000x reference)
//
#include <hip/hip_runtime.h>

#define N_TOKS 1024
#define N_ATOMS 4096
#define CS 384
#define CZ 128
#define CATOM 128
#define CPAIR 16
#define NQ 32
#define NK 128
#define NBLK 128          // N_ATOMS / NQ
#define KOFF (-48)        // NQ/2 - NK/2
#define KSEG 16
#define NSEG (NK / KSEG)  // 8
#define NB_A 256
#define NB_B (NBLK * NSEG) // 1024
#define LN_EPS 1e-5f

union alignas(16) SMem {
    struct {
        float ztile[NQ * KSEG * CPAIR];   // 32 KB
        int ends[N_TOKS];                 // 4 KB
        int tokq[NQ]; int tokk[KSEG];
        int qmap[NQ]; int kmap[KSEG];
        int uqtok[NQ]; int uktok[KSEG];
        float kvalid[KSEG];
        int uqk[2];
        int wsum[4];
    } b;
    struct {
        float xh[CS][4];                  // 6 KB
        float sacc[8][4][CATOM];          // 16 KB
        float s_l[4][CATOM];              // 2 KB
        int ends[N_TOKS];                 // 4 KB
        int wsum[4];
    } a;
};

// shuffle-based scan of na[0..1023] -> inclusive ends[] in LDS (2 barriers total)
__device__ __forceinline__ void scan_ends(const int* __restrict__ na, int* ends, int* wsum, int t) {
    int4 v = ((const int4*)na)[t];
    int e0 = v.x, e1 = e0 + v.y, e2 = e1 + v.z, e3 = e2 + v.w;
    int s = e3;
    int lane = t & 63, w = t >> 6;
    #pragma unroll
    for (int off = 1; off < 64; off <<= 1) {
        int u = __shfl_up(s, off);
        if (lane >= off) s += u;
    }
    if (lane == 63) wsum[w] = s;
    __syncthreads();
    int wbase = 0;
    #pragma unroll
    for (int i = 0; i < 4; i++) wbase += (i < w) ? wsum[i] : 0;
    int base = wbase + s - e3;
    ends[4 * t + 0] = base + e0;
    ends[4 * t + 1] = base + e1;
    ends[4 * t + 2] = base + e2;
    ends[4 * t + 3] = base + e3;
    __syncthreads();
}

__device__ __forceinline__ int bsearch_tok(const int* ends, int a) {
    int lo = 0, hi = N_TOKS - 1;
    while (lo < hi) { int mid = (lo + hi) >> 1; if (ends[mid] > a) hi = mid; else lo = mid + 1; }
    return lo;
}

__global__ __launch_bounds__(256, 4) void k_all(
        const int* __restrict__ na, const float* __restrict__ si,
        const float* __restrict__ lnw, const float* __restrict__ Ws,
        const float* __restrict__ bs, const float* __restrict__ mask,
        const float* __restrict__ cl, const float* __restrict__ rl,
        const float* __restrict__ Wr, const float* __restrict__ br,
        const float* __restrict__ zij, const float* __restrict__ lnzw,
        const float* __restrict__ Wz, const float* __restrict__ bz,
        const float* __restrict__ plm,
        float* __restrict__ cl_out, float* __restrict__ ql, float* __restrict__ plm_out) {
    __shared__ SMem sm;
    int t = threadIdx.x;
    int x = blockIdx.x;

    if (x < NB_A) {
        // ================= A role: s = LN(si)@Ws+bs ; cl_out ; ql =================
        int b = x, Tlo = b * 4;
        scan_ends(na, sm.a.ends, sm.a.wsum, t);
        // LN: 64 lanes per token
        {
            int tl = t >> 6, l = t & 63;
            const float4* row4 = (const float4*)(si + (size_t)(Tlo + tl) * CS);
            float4 v0 = row4[l];
            float4 v1 = make_float4(0.f, 0.f, 0.f, 0.f);
            if (l < 32) v1 = row4[64 + l];
            float sum = v0.x + v0.y + v0.z + v0.w + v1.x + v1.y + v1.z + v1.w;
            float sq = v0.x*v0.x + v0.y*v0.y + v0.z*v0.z + v0.w*v0.w
                     + v1.x*v1.x + v1.y*v1.y + v1.z*v1.z + v1.w*v1.w;
            #pragma unroll
            for (int m = 32; m >= 1; m >>= 1) { sum += __shfl_xor(sum, m); sq += __shfl_xor(sq, m); }
            float mu = sum * (1.f / CS);
            float rstd = rsqrtf(sq * (1.f / CS) - mu * mu + LN_EPS);
            float4 g0 = ((const float4*)lnw)[l];
            sm.a.xh[4*l+0][tl] = (v0.x - mu) * rstd * g0.x;
            sm.a.xh[4*l+1][tl] = (v0.y - mu) * rstd * g0.y;
            sm.a.xh[4*l+2][tl] = (v0.z - mu) * rstd * g0.z;
            sm.a.xh[4*l+3][tl] = (v0.w - mu) * rstd * g0.w;
            if (l < 32) {
                float4 g1 = ((const float4*)lnw)[64 + l];
                sm.a.xh[256+4*l+0][tl] = (v1.x - mu) * rstd * g1.x;
                sm.a.xh[256+4*l+1][tl] = (v1.y - mu) * rstd * g1.y;
                sm.a.xh[256+4*l+2][tl] = (v1.z - mu) * rstd * g1.z;
                sm.a.xh[256+4*l+3][tl] = (v1.w - mu) * rstd * g1.w;
            }
        }
        __syncthreads();
        // matvec c-split
        {
            int d4 = t & 31, cc = t >> 5;
            float4 a0 = make_float4(0,0,0,0), a1 = a0, a2 = a0, a3 = a0;
            const float4* Ws4 = (const float4*)Ws;
            int c0 = 48 * cc;
            #pragma unroll 4
            for (int c = c0; c < c0 + 48; c++) {
                float4 w = Ws4[(size_t)c * 32 + d4];
                float4 xv = *(const float4*)&sm.a.xh[c][0];
                a0.x += xv.x * w.x; a0.y += xv.x * w.y; a0.z += xv.x * w.z; a0.w += xv.x * w.w;
                a1.x += xv.y * w.x; a1.y += xv.y * w.y; a1.z += xv.y * w.z; a1.w += xv.y * w.w;
                a2.x += xv.z * w.x; a2.y += xv.z * w.y; a2.z += xv.z * w.z; a2.w += xv.z * w.w;
                a3.x += xv.w * w.x; a3.y += xv.w * w.y; a3.z += xv.w * w.z; a3.w += xv.w * w.w;
            }
            *(float4*)&sm.a.sacc[cc][0][d4 * 4] = a0;
            *(float4*)&sm.a.sacc[cc][1][d4 * 4] = a1;
            *(float4*)&sm.a.sacc[cc][2][d4 * 4] = a2;
            *(float4*)&sm.a.sacc[cc][3][d4 * 4] = a3;
        }
        __syncthreads();
        if (t < 128) {
            int tk = t >> 5, d = t & 31;
            float4 a = make_float4(0,0,0,0);
            #pragma unroll
            for (int cc = 0; cc < 8; cc++) {
                float4 p = *(const float4*)&sm.a.sacc[cc][tk][d * 4];
                a.x += p.x; a.y += p.y; a.z += p.z; a.w += p.w;
            }
            float4 bb = ((const float4*)bs)[d];
            float m = mask[Tlo + tk];
            a.x = (a.x + bb.x) * m; a.y = (a.y + bb.y) * m;
            a.z = (a.z + bb.z) * m; a.w = (a.w + bb.w) * m;
            *(float4*)&sm.a.s_l[tk][d * 4] = a;
        }
        __syncthreads();
        int elo = (Tlo == 0) ? 0 : sm.a.ends[Tlo - 1];
        int e_0 = sm.a.ends[Tlo], e_1 = sm.a.ends[Tlo + 1], e_2 = sm.a.ends[Tlo + 2];
        int ehi = (b == NB_A - 1) ? N_ATOMS : sm.a.ends[Tlo + 3];
        elo = min(max(elo, 0), N_ATOMS);
        ehi = min(max(ehi, 0), N_ATOMS);
        if (ehi < elo) ehi = elo;
        int items = (ehi - elo) * 32;
        for (int i = t; i < items; i += 256) {
            int a = elo + (i >> 5), d = i & 31;
            int tk = (a >= e_0) + (a >= e_1) + (a >= e_2);
            float4 c4 = ((const float4*)cl)[(size_t)a * 32 + d];
            float4 sv = *(const float4*)&sm.a.s_l[tk][d * 4];
            float4 co;
            co.x = c4.x + sv.x; co.y = c4.y + sv.y; co.z = c4.z + sv.z; co.w = c4.w + sv.w;
            float px = rl[a * 3 + 0], py = rl[a * 3 + 1], pz = rl[a * 3 + 2];
            float4 w0 = ((const float4*)Wr)[d];
            float4 w1 = ((const float4*)Wr)[32 + d];
            float4 w2 = ((const float4*)Wr)[64 + d];
            float4 bb = ((const float4*)br)[d];
            float4 q;
            q.x = co.x + px * w0.x + py * w1.x + pz * w2.x + bb.x;
            q.y = co.y + px * w0.y + py * w1.y + pz * w2.y + bb.y;
            q.z = co.z + px * w0.z + py * w1.z + pz * w2.z + bb.z;
            q.w = co.w + px * w0.w + py * w1.w + pz * w2.w + bb.w;
            ((float4*)cl_out)[(size_t)a * 32 + d] = co;
            ((float4*)ql)[(size_t)a * 32 + d] = q;
        }
        return;
    }

    // ================= B role: z at gathered pairs + plm stream =================
    int xb = x - NB_A;
    int blk = xb >> 3, kseg = xb & 7;
    scan_ends(na, sm.b.ends, sm.b.wsum, t);

    if (t < NQ) {
        sm.b.tokq[t] = bsearch_tok(sm.b.ends, blk * NQ + t);
    } else if (t >= 64 && t < 64 + KSEG) {
        int kk = t - 64;
        int kg = blk * NQ + KOFF + kseg * KSEG + kk;
        sm.b.kvalid[kk] = (kg >= 0 && kg < N_ATOMS) ? 1.0f : 0.0f;
        sm.b.tokk[kk] = bsearch_tok(sm.b.ends, min(max(kg, 0), N_ATOMS - 1));
    }
    __syncthreads();
    if (t == 0) {
        int u = 0;
        for (int q = 0; q < NQ; q++) { if (q == 0 || sm.b.tokq[q] != sm.b.tokq[q-1]) sm.b.uqtok[u++] = sm.b.tokq[q]; sm.b.qmap[q] = u - 1; }
        sm.b.uqk[0] = u;
    } else if (t == 64) {
        int u = 0;
        for (int k = 0; k < KSEG; k++) { if (k == 0 || sm.b.tokk[k] != sm.b.tokk[k-1]) sm.b.uktok[u++] = sm.b.tokk[k]; sm.b.kmap[k] = u - 1; }
        sm.b.uqk[1] = u;
    }
    __syncthreads();
    int uq = sm.b.uqk[0], uk = sm.b.uqk[1];
    int npairs = uq * uk;      // <= 512, typical ~40

    // phase 1: 4 lanes per pair, single zij pass, all-register
    int sl = t & 3;
    for (int pp = t >> 2; pp < npairs; pp += 64) {
        int qi = pp / uk, ki = pp - qi * uk;
        const float4* rp = (const float4*)(zij + ((size_t)sm.b.uqtok[qi] * N_TOKS + sm.b.uktok[ki]) * CZ + sl * 32);
        float xs[32];
        float sum = 0.f, sq = 0.f;
        #pragma unroll
        for (int i = 0; i < 8; i++) {
            float4 v = rp[i];
            xs[4*i+0] = v.x; xs[4*i+1] = v.y; xs[4*i+2] = v.z; xs[4*i+3] = v.w;
            sum += v.x + v.y + v.z + v.w;
            sq  += v.x*v.x + v.y*v.y + v.z*v.z + v.w*v.w;
        }
        sum += __shfl_xor(sum, 1); sq += __shfl_xor(sq, 1);
        sum += __shfl_xor(sum, 2); sq += __shfl_xor(sq, 2);
        float mu = sum * (1.f / CZ);
        float rstd = rsqrtf(sq * (1.f / CZ) - mu * mu + LN_EPS);
        // fold LN weight in place (lnzw chunk for this lane: [sl*32, sl*32+32))
        const float4* l4 = (const float4*)(lnzw + sl * 32);
        #pragma unroll
        for (int i = 0; i < 8; i++) {
            float4 g = l4[i];
            xs[4*i+0] = (xs[4*i+0] - mu) * rstd * g.x;
            xs[4*i+1] = (xs[4*i+1] - mu) * rstd * g.y;
            xs[4*i+2] = (xs[4*i+2] - mu) * rstd * g.z;
            xs[4*i+3] = (xs[4*i+3] - mu) * rstd * g.w;
        }
        float acc[16];
        #pragma unroll
        for (int d = 0; d < 16; d++) acc[d] = 0.f;
        #pragma unroll
        for (int j = 0; j < 32; j++) {
            float xv = xs[j];
            const float4* wp = (const float4*)(Wz + (sl * 32 + j) * CPAIR);
            float4 w0 = wp[0], w1 = wp[1], w2 = wp[2], w3 = wp[3];
            acc[ 0] += xv * w0.x; acc[ 1] += xv * w0.y; acc[ 2] += xv * w0.z; acc[ 3] += xv * w0.w;
            acc[ 4] += xv * w1.x; acc[ 5] += xv * w1.y; acc[ 6] += xv * w1.z; acc[ 7] += xv * w1.w;
            acc[ 8] += xv * w2.x; acc[ 9] += xv * w2.y; acc[10] += xv * w2.z; acc[11] += xv * w2.w;
            acc[12] += xv * w3.x; acc[13] += xv * w3.y; acc[14] += xv * w3.z; acc[15] += xv * w3.w;
        }
        #pragma unroll
        for (int d = 0; d < 16; d++) { acc[d] += __shfl_xor(acc[d], 1); acc[d] += __shfl_xor(acc[d], 2); }
        if (sl == 0) {
            float4 b0 = ((const float4*)bz)[0], b1 = ((const float4*)bz)[1];
            float4 b2 = ((const float4*)bz)[2], b3 = ((const float4*)bz)[3];
            float* zt = &sm.b.ztile[(qi * KSEG + ki) * CPAIR];
            float4 o0 = make_float4(acc[0]+b0.x, acc[1]+b0.y, acc[2]+b0.z, acc[3]+b0.w);
            float4 o1 = make_float4(acc[4]+b1.x, acc[5]+b1.y, acc[6]+b1.z, acc[7]+b1.w);
            float4 o2 = make_float4(acc[8]+b2.x, acc[9]+b2.y, acc[10]+b2.z, acc[11]+b2.w);
            float4 o3 = make_float4(acc[12]+b3.x, acc[13]+b3.y, acc[14]+b3.z, acc[15]+b3.w);
            *(float4*)&zt[0] = o0; *(float4*)&zt[4] = o1;
            *(float4*)&zt[8] = o2; *(float4*)&zt[12] = o3;
        }
    }
    __syncthreads();

    // phase 2: stream 32 q * 16 k * 16 d = 2048 float4
    const float4* plm4 = (const float4*)plm;
    float4* out4 = (float4*)plm_out;
    #pragma unroll
    for (int i = 0; i < 8; i++) {
        int f = t + i * 256;          // 0..2047
        int d4 = f & 3;
        int kk = (f >> 2) & 15;
        int q  = f >> 6;
        size_t g = ((size_t)(blk * NQ + q) * NK + (size_t)kseg * KSEG + kk) * (CPAIR / 4) + d4;
        float4 v = plm4[g];
        float vd = sm.b.kvalid[kk];
        const float4 z = *(const float4*)&sm.b.ztile[(sm.b.qmap[q] * KSEG + sm.b.kmap[kk]) * CPAIR + d4 * 4];
        v.x += vd * z.x; v.y += vd * z.y; v.z += vd * z.z; v.w += vd * z.w;
        out4[g] = v;
    }
}

extern "C" void kernel_launch(void* const* d_in, const int* in_sizes, int n_in,
                              void* d_out, int out_size, void* d_ws, size_t ws_size,
                              hipStream_t stream) {
    (void)in_sizes; (void)n_in; (void)out_size; (void)d_ws; (void)ws_size;
    const float* token_mask = (const float*)d_in[0];
    const int*   num_atoms  = (const int*)d_in[1];
    const float* cl   = (const float*)d_in[2];
    const float* plm  = (const float*)d_in[3];
    const float* si   = (const float*)d_in[4];
    const float* zij  = (const float*)d_in[5];
    const float* rl   = (const float*)d_in[6];
    const float* ln_s_w = (const float*)d_in[7];
    const float* W_s  = (const float*)d_in[8];
    const float* b_s  = (const float*)d_in[9];
    const float* ln_z_w = (const float*)d_in[10];
    const float* W_z  = (const float*)d_in[11];
    const float* b_z  = (const float*)d_in[12];
    const float* W_r  = (const float*)d_in[13];
    const float* b_r  = (const float*)d_in[14];

    float* out_cl  = (float*)d_out;
    float* out_plm = out_cl + (size_t)N_ATOMS * CATOM;
    float* out_ql  = out_plm + (size_t)NBLK * NQ * NK * CPAIR;

    k_all<<<NB_A + NB_B, 256, 0, stream>>>(num_atoms, si, ln_s_w, W_s, b_s, token_mask,
                                           cl, rl, W_r, b_r,
                                           zij, ln_z_w, W_z, b_z, plm,
                                           out_cl, out_ql, out_plm);
}

// Round 5
// 39.998 us; speedup vs baseline: 4.3142x; 4.3142x over previous
//
#include <hip/hip_runtime.h>

#define N_TOKS 1024
#define N_ATOMS 4096
#define CS 384
#define CZ 128
#define CATOM 128
#define CPAIR 16
#define NQ 32
#define NK 128
#define NBLK 128          // N_ATOMS / NQ
#define KOFF (-48)        // NQ/2 - NK/2
#define KSEG 32
#define NSEG (NK / KSEG)  // 4
#define NB_B (NBLK * NSEG) // 512, B-role blocks (x < NB_B)
#define NB_A 256           // A-role blocks
#define LN_EPS 1e-5f

union alignas(16) SMem {
    struct {
        float ztile[NQ * KSEG * CPAIR];   // 64 KB
        int ends[N_TOKS];                 // 4 KB
        int tokq[NQ]; int tokk[KSEG];
        int qmap[NQ]; int kmap[KSEG];
        int uqtok[NQ]; int uktok[KSEG];
        float kvalid[KSEG];
        int uqk[2];
        int wsum[4];
    } b;
    struct {
        float xh[CS][4];                  // 6 KB
        float sacc[8][4][CATOM];          // 16 KB
        float s_l[4][CATOM];              // 2 KB
        int ends[N_TOKS];                 // 4 KB
        int wsum[4];
    } a;
};

// shuffle-based scan of na[0..1023] -> inclusive ends[] in LDS (2 barriers)
__device__ __forceinline__ void scan_ends(const int* __restrict__ na, int* ends, int* wsum, int t) {
    int4 v = ((const int4*)na)[t];
    int e0 = v.x, e1 = e0 + v.y, e2 = e1 + v.z, e3 = e2 + v.w;
    int s = e3;
    int lane = t & 63, w = t >> 6;
    #pragma unroll
    for (int off = 1; off < 64; off <<= 1) {
        int u = __shfl_up(s, off);
        if (lane >= off) s += u;
    }
    if (lane == 63) wsum[w] = s;
    __syncthreads();
    int wbase = 0;
    #pragma unroll
    for (int i = 0; i < 4; i++) wbase += (i < w) ? wsum[i] : 0;
    int base = wbase + s - e3;
    ends[4 * t + 0] = base + e0;
    ends[4 * t + 1] = base + e1;
    ends[4 * t + 2] = base + e2;
    ends[4 * t + 3] = base + e3;
    __syncthreads();
}

__device__ __forceinline__ int bsearch_tok(const int* ends, int a) {
    int lo = 0, hi = N_TOKS - 1;
    while (lo < hi) { int mid = (lo + hi) >> 1; if (ends[mid] > a) hi = mid; else lo = mid + 1; }
    return lo;
}

__global__ __launch_bounds__(256) void k_all(
        const int* __restrict__ na, const float* __restrict__ si,
        const float* __restrict__ lnw, const float* __restrict__ Ws,
        const float* __restrict__ bs, const float* __restrict__ mask,
        const float* __restrict__ cl, const float* __restrict__ rl,
        const float* __restrict__ Wr, const float* __restrict__ br,
        const float* __restrict__ zij, const float* __restrict__ lnzw,
        const float* __restrict__ Wz, const float* __restrict__ bz,
        const float* __restrict__ plm,
        float* __restrict__ cl_out, float* __restrict__ ql, float* __restrict__ plm_out) {
    __shared__ SMem sm;
    int t = threadIdx.x;
    int x = blockIdx.x;

    if (x >= NB_B) {
        // ================= A role: s = LN(si)@Ws+bs ; cl_out ; ql =================
        int b = x - NB_B, Tlo = b * 4;
        scan_ends(na, sm.a.ends, sm.a.wsum, t);
        // LN: 64 lanes per token
        {
            int tl = t >> 6, l = t & 63;
            const float4* row4 = (const float4*)(si + (size_t)(Tlo + tl) * CS);
            float4 v0 = row4[l];
            float4 v1 = make_float4(0.f, 0.f, 0.f, 0.f);
            if (l < 32) v1 = row4[64 + l];
            float sum = v0.x + v0.y + v0.z + v0.w + v1.x + v1.y + v1.z + v1.w;
            float sq = v0.x*v0.x + v0.y*v0.y + v0.z*v0.z + v0.w*v0.w
                     + v1.x*v1.x + v1.y*v1.y + v1.z*v1.z + v1.w*v1.w;
            #pragma unroll
            for (int m = 32; m >= 1; m >>= 1) { sum += __shfl_xor(sum, m); sq += __shfl_xor(sq, m); }
            float mu = sum * (1.f / CS);
            float rstd = rsqrtf(sq * (1.f / CS) - mu * mu + LN_EPS);
            float4 g0 = ((const float4*)lnw)[l];
            sm.a.xh[4*l+0][tl] = (v0.x - mu) * rstd * g0.x;
            sm.a.xh[4*l+1][tl] = (v0.y - mu) * rstd * g0.y;
            sm.a.xh[4*l+2][tl] = (v0.z - mu) * rstd * g0.z;
            sm.a.xh[4*l+3][tl] = (v0.w - mu) * rstd * g0.w;
            if (l < 32) {
                float4 g1 = ((const float4*)lnw)[64 + l];
                sm.a.xh[256+4*l+0][tl] = (v1.x - mu) * rstd * g1.x;
                sm.a.xh[256+4*l+1][tl] = (v1.y - mu) * rstd * g1.y;
                sm.a.xh[256+4*l+2][tl] = (v1.z - mu) * rstd * g1.z;
                sm.a.xh[256+4*l+3][tl] = (v1.w - mu) * rstd * g1.w;
            }
        }
        __syncthreads();
        // matvec c-split: each Ws element loaded once per block
        {
            int d4 = t & 31, cc = t >> 5;
            float4 a0 = make_float4(0,0,0,0), a1 = a0, a2 = a0, a3 = a0;
            const float4* Ws4 = (const float4*)Ws;
            int c0 = 48 * cc;
            #pragma unroll 4
            for (int c = c0; c < c0 + 48; c++) {
                float4 w = Ws4[(size_t)c * 32 + d4];
                float4 xv = *(const float4*)&sm.a.xh[c][0];
                a0.x += xv.x * w.x; a0.y += xv.x * w.y; a0.z += xv.x * w.z; a0.w += xv.x * w.w;
                a1.x += xv.y * w.x; a1.y += xv.y * w.y; a1.z += xv.y * w.z; a1.w += xv.y * w.w;
                a2.x += xv.z * w.x; a2.y += xv.z * w.y; a2.z += xv.z * w.z; a2.w += xv.z * w.w;
                a3.x += xv.w * w.x; a3.y += xv.w * w.y; a3.z += xv.w * w.z; a3.w += xv.w * w.w;
            }
            *(float4*)&sm.a.sacc[cc][0][d4 * 4] = a0;
            *(float4*)&sm.a.sacc[cc][1][d4 * 4] = a1;
            *(float4*)&sm.a.sacc[cc][2][d4 * 4] = a2;
            *(float4*)&sm.a.sacc[cc][3][d4 * 4] = a3;
        }
        __syncthreads();
        if (t < 128) {
            int tk = t >> 5, d = t & 31;
            float4 a = make_float4(0,0,0,0);
            #pragma unroll
            for (int cc = 0; cc < 8; cc++) {
                float4 p = *(const float4*)&sm.a.sacc[cc][tk][d * 4];
                a.x += p.x; a.y += p.y; a.z += p.z; a.w += p.w;
            }
            float4 bb = ((const float4*)bs)[d];
            float m = mask[Tlo + tk];
            a.x = (a.x + bb.x) * m; a.y = (a.y + bb.y) * m;
            a.z = (a.z + bb.z) * m; a.w = (a.w + bb.w) * m;
            *(float4*)&sm.a.s_l[tk][d * 4] = a;
        }
        __syncthreads();
        int elo = (Tlo == 0) ? 0 : sm.a.ends[Tlo - 1];
        int e_0 = sm.a.ends[Tlo], e_1 = sm.a.ends[Tlo + 1], e_2 = sm.a.ends[Tlo + 2];
        int ehi = (b == NB_A - 1) ? N_ATOMS : sm.a.ends[Tlo + 3];
        elo = min(max(elo, 0), N_ATOMS);
        ehi = min(max(ehi, 0), N_ATOMS);
        if (ehi < elo) ehi = elo;
        int items = (ehi - elo) * 32;
        for (int i = t; i < items; i += 256) {
            int a = elo + (i >> 5), d = i & 31;
            int tk = (a >= e_0) + (a >= e_1) + (a >= e_2);
            float4 c4 = ((const float4*)cl)[(size_t)a * 32 + d];
            float4 sv = *(const float4*)&sm.a.s_l[tk][d * 4];
            float4 co;
            co.x = c4.x + sv.x; co.y = c4.y + sv.y; co.z = c4.z + sv.z; co.w = c4.w + sv.w;
            float px = rl[a * 3 + 0], py = rl[a * 3 + 1], pz = rl[a * 3 + 2];
            float4 w0 = ((const float4*)Wr)[d];
            float4 w1 = ((const float4*)Wr)[32 + d];
            float4 w2 = ((const float4*)Wr)[64 + d];
            float4 bb = ((const float4*)br)[d];
            float4 q;
            q.x = co.x + px * w0.x + py * w1.x + pz * w2.x + bb.x;
            q.y = co.y + px * w0.y + py * w1.y + pz * w2.y + bb.y;
            q.z = co.z + px * w0.z + py * w1.z + pz * w2.z + bb.z;
            q.w = co.w + px * w0.w + py * w1.w + pz * w2.w + bb.w;
            ((float4*)cl_out)[(size_t)a * 32 + d] = co;
            ((float4*)ql)[(size_t)a * 32 + d] = q;
        }
        return;
    }

    // ================= B role: z at gathered pairs + plm stream =================
    int blk = x >> 2, kseg = x & 3;
    scan_ends(na, sm.b.ends, sm.b.wsum, t);

    if (t < NQ) {
        sm.b.tokq[t] = bsearch_tok(sm.b.ends, blk * NQ + t);
    } else if (t >= 64 && t < 64 + KSEG) {
        int kk = t - 64;
        int kg = blk * NQ + KOFF + kseg * KSEG + kk;
        sm.b.kvalid[kk] = (kg >= 0 && kg < N_ATOMS) ? 1.0f : 0.0f;
        sm.b.tokk[kk] = bsearch_tok(sm.b.ends, min(max(kg, 0), N_ATOMS - 1));
    }
    __syncthreads();

    // ---- wave-parallel dedup via ballot (wave 0: q side, wave 1: k side) ----
    if (t < NQ) {
        int tq = sm.b.tokq[t];
        bool head = (t == 0) || (tq != sm.b.tokq[t - 1]);
        unsigned long long m = __ballot(head);
        int rank = (int)__popcll(m & ((2ull << t) - 1)) - 1;
        sm.b.qmap[t] = rank;
        if (head) sm.b.uqtok[rank] = tq;
        if (t == 0) sm.b.uqk[0] = (int)__popcll(m);
    } else if (t >= 64 && t < 64 + KSEG) {
        int lane = t - 64;
        int tk = sm.b.tokk[lane];
        bool head = (lane == 0) || (tk != sm.b.tokk[lane - 1]);
        unsigned long long m = __ballot(head);
        int rank = (int)__popcll(m & ((2ull << lane) - 1)) - 1;
        sm.b.kmap[lane] = rank;
        if (head) sm.b.uktok[rank] = tk;
        if (lane == 0) sm.b.uqk[1] = (int)__popcll(m);
    }
    __syncthreads();
    int uq = sm.b.uqk[0], uk = sm.b.uqk[1];
    int npairs = uq * uk;      // typical ~72

    // ---- prefetch phase-2 plm into registers (T14: issue early, consume late) ----
    const float4* plm4 = (const float4*)plm;
    float4 pv[16];
    #pragma unroll
    for (int i = 0; i < 16; i++) {
        int f = t + i * 256;          // 0..4095
        int d4 = f & 3;
        int kk = (f >> 2) & 31;
        int q  = f >> 7;
        size_t g = ((size_t)(blk * NQ + q) * NK + (size_t)kseg * KSEG + kk) * (CPAIR / 4) + d4;
        pv[i] = plm4[g];
    }

    // ---- phase 1: z at unique pairs, 1 lane per pair (register-lean, R0/R2-proven) ----
    for (int p = t; p < npairs; p += 256) {
        int qi = p / uk, ki = p - qi * uk;
        int tq = sm.b.uqtok[qi], tk = sm.b.uktok[ki];
        const float* row = zij + ((size_t)tq * N_TOKS + tk) * CZ;
        float sum = 0.f, sq = 0.f;
        for (int c4 = 0; c4 < CZ / 4; c4++) {
            float4 v = *(const float4*)(row + c4 * 4);
            sum += v.x + v.y + v.z + v.w;
            sq  += v.x * v.x + v.y * v.y + v.z * v.z + v.w * v.w;
        }
        float mu = sum * (1.f / CZ);
        float rstd = rsqrtf(sq * (1.f / CZ) - mu * mu + LN_EPS);
        float acc[CPAIR];
        #pragma unroll
        for (int d = 0; d < CPAIR; d++) acc[d] = bz[d];
        for (int c4 = 0; c4 < CZ / 4; c4++) {
            float4 v = *(const float4*)(row + c4 * 4);
            float xs4[4] = {v.x, v.y, v.z, v.w};
            #pragma unroll
            for (int j = 0; j < 4; j++) {
                int c = c4 * 4 + j;
                float xv = (xs4[j] - mu) * rstd * lnzw[c];
                const float* wrow = Wz + c * CPAIR;
                #pragma unroll
                for (int d = 0; d < CPAIR; d++) acc[d] += xv * wrow[d];
            }
        }
        float* zt = &sm.b.ztile[(qi * KSEG + ki) * CPAIR];
        #pragma unroll
        for (int d = 0; d < CPAIR; d++) zt[d] = acc[d];
    }
    __syncthreads();

    // ---- phase 2: add z to prefetched plm, store ----
    float4* out4 = (float4*)plm_out;
    #pragma unroll
    for (int i = 0; i < 16; i++) {
        int f = t + i * 256;
        int d4 = f & 3;
        int kk = (f >> 2) & 31;
        int q  = f >> 7;
        size_t g = ((size_t)(blk * NQ + q) * NK + (size_t)kseg * KSEG + kk) * (CPAIR / 4) + d4;
        float vd = sm.b.kvalid[kk];
        const float4 z = *(const float4*)&sm.b.ztile[(sm.b.qmap[q] * KSEG + sm.b.kmap[kk]) * CPAIR + d4 * 4];
        float4 v = pv[i];
        v.x += vd * z.x; v.y += vd * z.y; v.z += vd * z.z; v.w += vd * z.w;
        out4[g] = v;
    }
}

extern "C" void kernel_launch(void* const* d_in, const int* in_sizes, int n_in,
                              void* d_out, int out_size, void* d_ws, size_t ws_size,
                              hipStream_t stream) {
    (void)in_sizes; (void)n_in; (void)out_size; (void)d_ws; (void)ws_size;
    const float* token_mask = (const float*)d_in[0];
    const int*   num_atoms  = (const int*)d_in[1];
    const float* cl   = (const float*)d_in[2];
    const float* plm  = (const float*)d_in[3];
    const float* si   = (const float*)d_in[4];
    const float* zij  = (const float*)d_in[5];
    const float* rl   = (const float*)d_in[6];
    const float* ln_s_w = (const float*)d_in[7];
    const float* W_s  = (const float*)d_in[8];
    const float* b_s  = (const float*)d_in[9];
    const float* ln_z_w = (const float*)d_in[10];
    const float* W_z  = (const float*)d_in[11];
    const float* b_z  = (const float*)d_in[12];
    const float* W_r  = (const float*)d_in[13];
    const float* b_r  = (const float*)d_in[14];

    float* out_cl  = (float*)d_out;
    float* out_plm = out_cl + (size_t)N_ATOMS * CATOM;
    float* out_ql  = out_plm + (size_t)NBLK * NQ * NK * CPAIR;

    k_all<<<NB_B + NB_A, 256, 0, stream>>>(num_atoms, si, ln_s_w, W_s, b_s, token_mask,
                                           cl, rl, W_r, b_r,
                                           zij, ln_z_w, W_z, b_z, plm,
                                           out_cl, out_ql, out_plm);
}